// Round 1
// baseline (874.552 us; speedup 1.0000x reference)
//
#include <hip/hip_runtime.h>
#include <hip/hip_bf16.h>
#include <stdint.h>

#define BDIM 8192
#define HDIM 2048
#define KDIM 4096   // IN + H
#define BM 128
#define BN 64       // per gate
#define BK 64

using f32x4  = __attribute__((ext_vector_type(4))) float;
using bf16x8 = __attribute__((ext_vector_type(8))) short;

__device__ __forceinline__ uint16_t f2bf(float f) {
    union { float f; uint32_t u; } v;
    v.f = f;
    uint32_t r = v.u + 0x7fffu + ((v.u >> 16) & 1u);  // RNE
    return (uint16_t)(r >> 16);
}

__device__ __forceinline__ float fast_sigmoid(float x) {
    return 1.0f / (1.0f + __expf(-x));
}

__device__ __forceinline__ float fast_tanh(float x) {
    float ax = fabsf(x);
    float t = __expf(-2.0f * ax);
    float r = (1.0f - t) / (1.0f + t);
    return copysignf(r, x);
}

// Build xh = concat(x, h) as bf16 [8192][4096]
__global__ void cvt_xh_kernel(const float* __restrict__ x,
                              const float* __restrict__ h,
                              uint16_t* __restrict__ xh) {
    const int64_t total = (int64_t)BDIM * KDIM / 4;
    for (int64_t i = (int64_t)blockIdx.x * blockDim.x + threadIdx.x; i < total;
         i += (int64_t)gridDim.x * blockDim.x) {
        int64_t e = i << 2;
        int b = (int)(e >> 12);
        int k = (int)(e & 4095);
        float4 v;
        if (k < 2048) v = *(const float4*)(x + (int64_t)b * 2048 + k);
        else          v = *(const float4*)(h + (int64_t)b * 2048 + (k - 2048));
        ushort4 o;
        o.x = f2bf(v.x); o.y = f2bf(v.y); o.z = f2bf(v.z); o.w = f2bf(v.w);
        *(ushort4*)(xh + e) = o;
    }
}

// Build Wb = [W_f; W_o; W_c] as bf16 [3][2048][4096]
__global__ void cvt_w_kernel(const float* __restrict__ Wf,
                             const float* __restrict__ Wo,
                             const float* __restrict__ Wc,
                             uint16_t* __restrict__ Wb) {
    const int64_t per_gate = (int64_t)HDIM * KDIM;
    const int64_t total = 3 * per_gate / 4;
    for (int64_t i = (int64_t)blockIdx.x * blockDim.x + threadIdx.x; i < total;
         i += (int64_t)gridDim.x * blockDim.x) {
        int64_t e = i << 2;
        int gate = (int)(e / per_gate);
        int64_t rem = e - (int64_t)gate * per_gate;
        const float* src = (gate == 0) ? Wf : (gate == 1) ? Wo : Wc;
        float4 v = *(const float4*)(src + rem);
        ushort4 o;
        o.x = f2bf(v.x); o.y = f2bf(v.y); o.z = f2bf(v.z); o.w = f2bf(v.w);
        *(ushort4*)(Wb + e) = o;
    }
}

// GEMM over 3 gates with fused LSTM epilogue.
// A: xh bf16 [8192][4096]; Wb: bf16 [3][2048][4096] (row-major over K => B^T layout)
// Each block: 128 rows x 64 cols x 3 gates. 4 waves as 2x2.
__global__ __launch_bounds__(256) void lstm_gemm_kernel(
    const uint16_t* __restrict__ A,
    const uint16_t* __restrict__ Wb,
    const float* __restrict__ b_f, const float* __restrict__ b_o,
    const float* __restrict__ b_c,
    const float* __restrict__ c_prev,
    float* __restrict__ h_out, float* __restrict__ c_out) {
    __shared__ uint16_t ldsA[BM * BK];      // 16 KiB
    __shared__ uint16_t ldsB[3 * BN * BK];  // 24 KiB

    const int tid  = threadIdx.x;
    const int lane = tid & 63;
    const int wave = tid >> 6;
    const int wm = wave >> 1;   // 0..1 -> 64-row half
    const int wn = wave & 1;    // 0..1 -> 32-col half
    const int frow = lane & 15;
    const int kgrp = lane >> 4;

    const int mb = blockIdx.x >> 5;  // 64 row-blocks
    const int nb = blockIdx.x & 31;  // 32 col-blocks
    const int m0 = mb * BM;
    const int n0 = nb * BN;

    f32x4 acc[3][4][2] = {};  // [gate][mf][nf]

    for (int k0 = 0; k0 < KDIM; k0 += BK) {
        // ---- stage A tile: 1024 chunks of 16B, linear LDS dest,
        //      XOR-swizzled global source (rule #21) ----
#pragma unroll
        for (int c = 0; c < 4; ++c) {
            const int chunk = c * 256 + tid;
            const int row = chunk >> 3;
            const int cc  = chunk & 7;
            const int scc = cc ^ (row & 7);
            const uint16_t* src = A + (m0 + row) * KDIM + k0 + scc * 8;
            __builtin_amdgcn_global_load_lds(
                (__attribute__((address_space(1))) void*)(src),
                (__attribute__((address_space(3))) void*)(ldsA + (c * 256 + wave * 64) * 8),
                16, 0, 0);
        }
        // ---- stage B tiles (3 gates): 1536 chunks ----
#pragma unroll
        for (int c = 0; c < 6; ++c) {
            const int chunk = c * 256 + tid;
            const int gate = chunk >> 9;
            const int row  = (chunk >> 3) & 63;
            const int cc   = chunk & 7;
            const int scc  = cc ^ (row & 7);
            const uint16_t* src = Wb + gate * (HDIM * KDIM) + (n0 + row) * KDIM + k0 + scc * 8;
            __builtin_amdgcn_global_load_lds(
                (__attribute__((address_space(1))) void*)(src),
                (__attribute__((address_space(3))) void*)(ldsB + (c * 256 + wave * 64) * 8),
                16, 0, 0);
        }
        __syncthreads();  // drains vmcnt before barrier (compiler-emitted)

#pragma unroll
        for (int kk = 0; kk < 2; ++kk) {
            bf16x8 af[4];
#pragma unroll
            for (int mf = 0; mf < 4; ++mf) {
                const int row = wm * 64 + mf * 16 + frow;
                const int sc = (kk * 4 + kgrp) ^ (row & 7);
                af[mf] = *(const bf16x8*)(ldsA + row * BK + sc * 8);
            }
#pragma unroll
            for (int g = 0; g < 3; ++g) {
#pragma unroll
                for (int nf = 0; nf < 2; ++nf) {
                    const int row = wn * 32 + nf * 16 + frow;
                    const int sc = (kk * 4 + kgrp) ^ (row & 7);
                    const bf16x8 bfr = *(const bf16x8*)(ldsB + g * (BN * BK) + row * BK + sc * 8);
#pragma unroll
                    for (int mf = 0; mf < 4; ++mf) {
                        acc[g][mf][nf] = __builtin_amdgcn_mfma_f32_16x16x32_bf16(
                            af[mf], bfr, acc[g][mf][nf], 0, 0, 0);
                    }
                }
            }
        }
        __syncthreads();
    }

    // ---- fused LSTM epilogue ----
    // C/D layout: col = lane&15, row = (lane>>4)*4 + j  [m89]
#pragma unroll
    for (int nf = 0; nf < 2; ++nf) {
        const int n = n0 + wn * 32 + nf * 16 + frow;
        const float bfv = b_f[n];
        const float bov = b_o[n];
        const float bcv = b_c[n];
#pragma unroll
        for (int mf = 0; mf < 4; ++mf) {
#pragma unroll
            for (int j = 0; j < 4; ++j) {
                const int m = m0 + wm * 64 + mf * 16 + kgrp * 4 + j;
                const float fpre = acc[0][mf][nf][j] + bfv;
                const float opre = acc[1][mf][nf][j] + bov;
                const float cpre = acc[2][mf][nf][j] + bcv;
                const float ft = fast_sigmoid(fpre);
                const float ot = fast_sigmoid(opre);
                const float ch = fast_tanh(cpre);
                const float cp = c_prev[m * HDIM + n];
                const float ct = ft * cp + (1.0f - ft) * ch;
                const float ht = ot * fast_tanh(ct);
                h_out[m * HDIM + n] = ht;
                c_out[m * HDIM + n] = ct;
            }
        }
    }
}

extern "C" void kernel_launch(void* const* d_in, const int* in_sizes, int n_in,
                              void* d_out, int out_size, void* d_ws, size_t ws_size,
                              hipStream_t stream) {
    const float* x_t   = (const float*)d_in[0];
    const float* h_t_1 = (const float*)d_in[1];
    const float* c_t_1 = (const float*)d_in[2];
    const float* W_f   = (const float*)d_in[3];
    const float* b_f   = (const float*)d_in[4];
    const float* W_o   = (const float*)d_in[5];
    const float* b_o   = (const float*)d_in[6];
    const float* W_c   = (const float*)d_in[7];
    const float* b_c   = (const float*)d_in[8];

    uint16_t* xh = (uint16_t*)d_ws;                    // 64 MiB
    uint16_t* Wbf = xh + (size_t)BDIM * KDIM;          // 48 MiB

    float* h_out = (float*)d_out;
    float* c_out = h_out + (size_t)BDIM * HDIM;

    cvt_xh_kernel<<<2048, 256, 0, stream>>>(x_t, h_t_1, xh);
    cvt_w_kernel<<<2048, 256, 0, stream>>>(W_f, W_o, W_c, Wbf);
    lstm_gemm_kernel<<<2048, 256, 0, stream>>>(xh, Wbf, b_f, b_o, b_c, c_t_1,
                                               h_out, c_out);
}

// Round 2
// 512.097 us; speedup vs baseline: 1.7078x; 1.7078x over previous
//
#include <hip/hip_runtime.h>
#include <hip/hip_bf16.h>
#include <stdint.h>

#define BDIM 8192
#define HDIM 2048
#define KDIM 4096   // IN + H
#define NDIM 6144   // 3 * H

using f32x4  = __attribute__((ext_vector_type(4))) float;
using bf16x8 = __attribute__((ext_vector_type(8))) short;
using short8 = __attribute__((ext_vector_type(8))) short;

__device__ __forceinline__ uint16_t f2bf(float f) {
    union { float f; uint32_t u; } v;
    v.f = f;
    uint32_t r = v.u + 0x7fffu + ((v.u >> 16) & 1u);  // RNE
    return (uint16_t)(r >> 16);
}

__device__ __forceinline__ float bf2f(uint16_t u) {
    union { uint32_t u; float f; } v;
    v.u = ((uint32_t)u) << 16;
    return v.f;
}

__device__ __forceinline__ float fast_sigmoid(float x) {
    return 1.0f / (1.0f + __expf(-x));
}

__device__ __forceinline__ float fast_tanh(float x) {
    float ax = fabsf(x);
    float t = __expf(-2.0f * ax);
    float r = (1.0f - t) / (1.0f + t);
    return copysignf(r, x);
}

// ---------------- conversion kernels ----------------

__global__ void cvt_xh_kernel(const float* __restrict__ x,
                              const float* __restrict__ h,
                              uint16_t* __restrict__ xh) {
    const int64_t total = (int64_t)BDIM * KDIM / 4;
    for (int64_t i = (int64_t)blockIdx.x * blockDim.x + threadIdx.x; i < total;
         i += (int64_t)gridDim.x * blockDim.x) {
        int64_t e = i << 2;
        int b = (int)(e >> 12);
        int k = (int)(e & 4095);
        float4 v;
        if (k < 2048) v = *(const float4*)(x + (int64_t)b * 2048 + k);
        else          v = *(const float4*)(h + (int64_t)b * 2048 + (k - 2048));
        ushort4 o;
        o.x = f2bf(v.x); o.y = f2bf(v.y); o.z = f2bf(v.z); o.w = f2bf(v.w);
        *(ushort4*)(xh + e) = o;
    }
}

__global__ void cvt_w_kernel(const float* __restrict__ Wf,
                             const float* __restrict__ Wo,
                             const float* __restrict__ Wc,
                             uint16_t* __restrict__ Wb) {
    const int64_t per_gate = (int64_t)HDIM * KDIM;
    const int64_t total = 3 * per_gate / 4;
    for (int64_t i = (int64_t)blockIdx.x * blockDim.x + threadIdx.x; i < total;
         i += (int64_t)gridDim.x * blockDim.x) {
        int64_t e = i << 2;
        int gate = (int)(e / per_gate);
        int64_t rem = e - (int64_t)gate * per_gate;
        const float* src = (gate == 0) ? Wf : (gate == 1) ? Wo : Wc;
        float4 v = *(const float4*)(src + rem);
        ushort4 o;
        o.x = f2bf(v.x); o.y = f2bf(v.y); o.z = f2bf(v.z); o.w = f2bf(v.w);
        *(ushort4*)(Wb + e) = o;
    }
}

// ---------------- 256x256 8-phase GEMM ----------------
// A: [8192][4096] bf16, Wb: [6144][4096] bf16 (B^T), G out: [8192][6144] bf16
// 8 waves (2M x 4N), per-wave C = 128x64. BK=64.
// LDS ring: 8 slots of [128 rows][64 cols] bf16 (16 KiB each) = 128 KiB.
//   A slots: even tile h0->0 h1->1, odd tile h0->2 h1->3
//   B slots: even tile h0->4 h1->5, odd tile h0->6 h1->7
// A-half h rows (within 256-tile): {wm*128 + h*64 + r}, slot row s = wm*64+r
// B-half h rows: {wn*64 + h*32 + r}, slot row s = wn*32+r
// XOR swizzle: 16B chunk c at row s lives at chunk (c ^ (s&7)); applied on the
// per-lane GLOBAL source (linear LDS dest for global_load_lds) and on ds_read.

#define STAGE_A(slot, t, h) do { \
    _Pragma("unroll") for (int q_ = 0; q_ < 2; ++q_) { \
        const int r_ = s_row[q_]; \
        const uint16_t* src_ = A + (int64_t)(m0 + ((r_ >> 6) << 7) + ((h) << 6) + (r_ & 63)) * KDIM + ((t) << 6) + s_kc[q_]; \
        __builtin_amdgcn_global_load_lds((__attribute__((address_space(1))) void*)(src_), \
            (__attribute__((address_space(3))) void*)(&lds[slot][(q_ * 512 + tid) * 8]), 16, 0, 0); \
    } } while (0)

#define STAGE_B(slot, t, h) do { \
    _Pragma("unroll") for (int q_ = 0; q_ < 2; ++q_) { \
        const int r_ = s_row[q_]; \
        const uint16_t* src_ = Wb + (int64_t)(n0 + ((r_ >> 5) << 6) + ((h) << 5) + (r_ & 31)) * KDIM + ((t) << 6) + s_kc[q_]; \
        __builtin_amdgcn_global_load_lds((__attribute__((address_space(1))) void*)(src_), \
            (__attribute__((address_space(3))) void*)(&lds[slot][(q_ * 512 + tid) * 8]), 16, 0, 0); \
    } } while (0)

// read logical (slot, srow, kchunk) with swizzle
#define RD(slot, srow, kc) \
    (*(const bf16x8*)((const char*)(&lds[0][0]) + ((slot) * 16384) + ((srow) * 128) + ((((kc) ^ ((srow) & 7))) * 16)))

#define PHASE(tp, qm, qn, STAGE_STMT, WAITC) do { \
    asm volatile("" ::: "memory"); \
    const int as_ = (((tp) & 1) << 1) + (qm); \
    const int bs_ = 4 + (((tp) & 1) << 1) + (qn); \
    bf16x8 a_[2][4]; \
    bf16x8 b_[2][2]; \
    _Pragma("unroll") for (int kk = 0; kk < 2; ++kk) { \
        _Pragma("unroll") for (int mf = 0; mf < 4; ++mf) \
            a_[kk][mf] = RD(as_, wm * 64 + mf * 16 + fr, kk * 4 + kg); \
        _Pragma("unroll") for (int nf = 0; nf < 2; ++nf) \
            b_[kk][nf] = RD(bs_, wn * 32 + nf * 16 + fr, kk * 4 + kg); \
    } \
    STAGE_STMT; \
    asm volatile("" ::: "memory"); \
    __builtin_amdgcn_s_barrier(); \
    asm volatile("s_waitcnt lgkmcnt(0)" ::: "memory"); \
    __builtin_amdgcn_s_setprio(1); \
    _Pragma("unroll") for (int kk = 0; kk < 2; ++kk) \
        _Pragma("unroll") for (int mf = 0; mf < 4; ++mf) \
            _Pragma("unroll") for (int nf = 0; nf < 2; ++nf) \
                acc[(qm) * 4 + mf][(qn) * 2 + nf] = __builtin_amdgcn_mfma_f32_16x16x32_bf16( \
                    a_[kk][mf], b_[kk][nf], acc[(qm) * 4 + mf][(qn) * 2 + nf], 0, 0, 0); \
    __builtin_amdgcn_s_setprio(0); \
    WAITC; \
    __builtin_amdgcn_s_barrier(); \
} while (0)

__global__ __launch_bounds__(512, 2) void lstm_gemm8p_kernel(
    const uint16_t* __restrict__ A,
    const uint16_t* __restrict__ Wb,
    uint16_t* __restrict__ G) {
    __shared__ uint16_t lds[8][8192];  // 128 KiB

    const int tid = threadIdx.x;
    const int lane = tid & 63;
    const int kg = lane >> 4;
    const int fr = lane & 15;
    const int wid = tid >> 6;
    const int wm = wid >> 2;   // 0..1
    const int wn = wid & 3;    // 0..3

    // XCD-aware swizzle: 768 blocks, 768 % 8 == 0 -> simple bijection
    const int bid = blockIdx.x;
    const int swz = (bid & 7) * 96 + (bid >> 3);
    const int mb = swz / 24;
    const int nb = swz - mb * 24;
    const int m0 = mb << 8;
    const int n0 = nb << 8;

    // staging constants: chunk = q*512 + tid -> row, swizzled k-chunk
    int s_row[2], s_kc[2];
#pragma unroll
    for (int q_ = 0; q_ < 2; ++q_) {
        const int chunk = q_ * 512 + tid;
        const int r_ = chunk >> 3;
        const int c_ = chunk & 7;
        s_row[q_] = r_;
        s_kc[q_] = (c_ ^ (r_ & 7)) * 8;  // element offset
    }

    f32x4 acc[8][4] = {};

    // prologue: tile0 (slots 0,4,1,5) + tile1 h0 (slots 2,6)
    STAGE_A(0, 0, 0); STAGE_B(4, 0, 0);
    STAGE_A(1, 0, 1); STAGE_B(5, 0, 1);
    STAGE_A(2, 1, 0); STAGE_B(6, 1, 0);
    asm volatile("s_waitcnt vmcnt(4)" ::: "memory");
    __builtin_amdgcn_s_barrier();

    // 64 K-tiles, 2 per iteration; last iteration (i=31) is the peeled tail
    for (int i = 0; i < 31; ++i) {
        const int t0 = 2 * i;
        const int t1 = t0 + 1, t2 = t0 + 2, t3 = t0 + 3;
        PHASE(t0, 0, 0, STAGE_A(3, t1, 1), );
        PHASE(t0, 0, 1, STAGE_B(7, t1, 1), );
        PHASE(t0, 1, 0, STAGE_A(0, t2, 0), );
        PHASE(t0, 1, 1, STAGE_B(4, t2, 0), asm volatile("s_waitcnt vmcnt(4)" ::: "memory"));
        PHASE(t1, 0, 0, STAGE_A(1, t2, 1), );
        PHASE(t1, 0, 1, STAGE_B(5, t2, 1), );
        PHASE(t1, 1, 0, STAGE_A(2, t3, 0), );
        PHASE(t1, 1, 1, STAGE_B(6, t3, 0), asm volatile("s_waitcnt vmcnt(4)" ::: "memory"));
    }
    // tail: t0=62, t1=63; no staging beyond K
    PHASE(62, 0, 0, STAGE_A(3, 63, 1), );
    PHASE(62, 0, 1, STAGE_B(7, 63, 1), );
    PHASE(62, 1, 0, ;, );
    PHASE(62, 1, 1, ;, asm volatile("s_waitcnt vmcnt(0)" ::: "memory"));
    PHASE(63, 0, 0, ;, );
    PHASE(63, 0, 1, ;, );
    PHASE(63, 1, 0, ;, );
    PHASE(63, 1, 1, ;, );

    // C-write: D layout col = lane&15, row = (lane>>4)*4 + j
#pragma unroll
    for (int mf = 0; mf < 8; ++mf) {
#pragma unroll
        for (int nf = 0; nf < 4; ++nf) {
            const int n = n0 + wn * 64 + nf * 16 + fr;
            const int64_t mbase = (int64_t)(m0 + wm * 128 + mf * 16 + kg * 4);
#pragma unroll
            for (int j = 0; j < 4; ++j) {
                G[(mbase + j) * NDIM + n] = f2bf(acc[mf][nf][j]);
            }
        }
    }
}

// ---------------- LSTM elementwise epilogue ----------------

__global__ void lstm_epi_kernel(const uint16_t* __restrict__ G,
                                const float* __restrict__ c_prev,
                                const float* __restrict__ b_f,
                                const float* __restrict__ b_o,
                                const float* __restrict__ b_c,
                                float* __restrict__ h_out,
                                float* __restrict__ c_out) {
    const int64_t total = (int64_t)BDIM * HDIM / 8;
    for (int64_t i = (int64_t)blockIdx.x * blockDim.x + threadIdx.x; i < total;
         i += (int64_t)gridDim.x * blockDim.x) {
        const int64_t e = i << 3;
        const int m = (int)(e >> 11);
        const int n = (int)(e & 2047);
        const int64_t gb = (int64_t)m * NDIM + n;
        const short8 fv = *(const short8*)(G + gb);
        const short8 ov = *(const short8*)(G + gb + HDIM);
        const short8 cv = *(const short8*)(G + gb + 2 * HDIM);
        const float4 cp0 = *(const float4*)(c_prev + (int64_t)m * HDIM + n);
        const float4 cp1 = *(const float4*)(c_prev + (int64_t)m * HDIM + n + 4);
        float cp[8] = {cp0.x, cp0.y, cp0.z, cp0.w, cp1.x, cp1.y, cp1.z, cp1.w};
        float hr[8], cr[8];
#pragma unroll
        for (int j = 0; j < 8; ++j) {
            const float fpre = bf2f((uint16_t)fv[j]) + b_f[n + j];
            const float opre = bf2f((uint16_t)ov[j]) + b_o[n + j];
            const float cpre = bf2f((uint16_t)cv[j]) + b_c[n + j];
            const float ft = fast_sigmoid(fpre);
            const float ot = fast_sigmoid(opre);
            const float ch = fast_tanh(cpre);
            const float ct = ft * cp[j] + (1.0f - ft) * ch;
            hr[j] = ot * fast_tanh(ct);
            cr[j] = ct;
        }
        float4 h0 = {hr[0], hr[1], hr[2], hr[3]};
        float4 h1 = {hr[4], hr[5], hr[6], hr[7]};
        float4 c0 = {cr[0], cr[1], cr[2], cr[3]};
        float4 c1 = {cr[4], cr[5], cr[6], cr[7]};
        *(float4*)(h_out + (int64_t)m * HDIM + n) = h0;
        *(float4*)(h_out + (int64_t)m * HDIM + n + 4) = h1;
        *(float4*)(c_out + (int64_t)m * HDIM + n) = c0;
        *(float4*)(c_out + (int64_t)m * HDIM + n + 4) = c1;
    }
}

extern "C" void kernel_launch(void* const* d_in, const int* in_sizes, int n_in,
                              void* d_out, int out_size, void* d_ws, size_t ws_size,
                              hipStream_t stream) {
    const float* x_t   = (const float*)d_in[0];
    const float* h_t_1 = (const float*)d_in[1];
    const float* c_t_1 = (const float*)d_in[2];
    const float* W_f   = (const float*)d_in[3];
    const float* b_f   = (const float*)d_in[4];
    const float* W_o   = (const float*)d_in[5];
    const float* b_o   = (const float*)d_in[6];
    const float* W_c   = (const float*)d_in[7];
    const float* b_c   = (const float*)d_in[8];

    uint16_t* xh  = (uint16_t*)d_ws;                            // 64 MiB
    uint16_t* Wbf = xh + (size_t)BDIM * KDIM;                   // 48 MiB
    uint16_t* G   = Wbf + (size_t)NDIM * KDIM;                  // 96 MiB

    float* h_out = (float*)d_out;
    float* c_out = h_out + (size_t)BDIM * HDIM;

    cvt_xh_kernel<<<2048, 256, 0, stream>>>(x_t, h_t_1, xh);
    cvt_w_kernel<<<2048, 256, 0, stream>>>(W_f, W_o, W_c, Wbf);
    lstm_gemm8p_kernel<<<768, 512, 0, stream>>>(xh, Wbf, G);
    lstm_epi_kernel<<<2048, 256, 0, stream>>>(G, c_t_1, b_f, b_o, b_c,
                                              h_out, c_out);
}

// Round 3
// 473.586 us; speedup vs baseline: 1.8467x; 1.0813x over previous
//
#include <hip/hip_runtime.h>
#include <hip/hip_bf16.h>
#include <stdint.h>

#define BDIM 8192
#define HDIM 2048
#define KDIM 4096   // IN + H
#define NDIM 6144   // 3 * H

using f32x4  = __attribute__((ext_vector_type(4))) float;
using bf16x8 = __attribute__((ext_vector_type(8))) short;
using short8 = __attribute__((ext_vector_type(8))) short;

__device__ __forceinline__ uint16_t f2bf(float f) {
    union { float f; uint32_t u; } v;
    v.f = f;
    uint32_t r = v.u + 0x7fffu + ((v.u >> 16) & 1u);  // RNE
    return (uint16_t)(r >> 16);
}

__device__ __forceinline__ float bf2f(uint16_t u) {
    union { uint32_t u; float f; } v;
    v.u = ((uint32_t)u) << 16;
    return v.f;
}

__device__ __forceinline__ float fast_sigmoid(float x) {
    return 1.0f / (1.0f + __expf(-x));
}

__device__ __forceinline__ float fast_tanh(float x) {
    float ax = fabsf(x);
    float t = __expf(-2.0f * ax);
    float r = (1.0f - t) / (1.0f + t);
    return copysignf(r, x);
}

// ---------------- conversion kernels ----------------

__global__ void cvt_xh_kernel(const float* __restrict__ x,
                              const float* __restrict__ h,
                              uint16_t* __restrict__ xh) {
    const int64_t total = (int64_t)BDIM * KDIM / 4;
    for (int64_t i = (int64_t)blockIdx.x * blockDim.x + threadIdx.x; i < total;
         i += (int64_t)gridDim.x * blockDim.x) {
        int64_t e = i << 2;
        int b = (int)(e >> 12);
        int k = (int)(e & 4095);
        float4 v;
        if (k < 2048) v = *(const float4*)(x + (int64_t)b * 2048 + k);
        else          v = *(const float4*)(h + (int64_t)b * 2048 + (k - 2048));
        ushort4 o;
        o.x = f2bf(v.x); o.y = f2bf(v.y); o.z = f2bf(v.z); o.w = f2bf(v.w);
        *(ushort4*)(xh + e) = o;
    }
}

__global__ void cvt_w_kernel(const float* __restrict__ Wf,
                             const float* __restrict__ Wo,
                             const float* __restrict__ Wc,
                             uint16_t* __restrict__ Wb) {
    const int64_t per_gate = (int64_t)HDIM * KDIM;
    const int64_t total = 3 * per_gate / 4;
    for (int64_t i = (int64_t)blockIdx.x * blockDim.x + threadIdx.x; i < total;
         i += (int64_t)gridDim.x * blockDim.x) {
        int64_t e = i << 2;
        int gate = (int)(e / per_gate);
        int64_t rem = e - (int64_t)gate * per_gate;
        const float* src = (gate == 0) ? Wf : (gate == 1) ? Wo : Wc;
        float4 v = *(const float4*)(src + rem);
        ushort4 o;
        o.x = f2bf(v.x); o.y = f2bf(v.y); o.z = f2bf(v.z); o.w = f2bf(v.w);
        *(ushort4*)(Wb + e) = o;
    }
}

// ---------------- 256x256 8-phase GEMM (fragment-reuse schedule) ----------
// A: [8192][4096] bf16, Wb: [6144][4096] bf16 (B^T), G out: [8192][6144] bf16
// 8 waves (2M x 4N), per-wave C = 128x64. BK=64.
// LDS ring: 8 slots of [128 rows][64 cols] bf16 (16 KiB each) = 128 KiB.
//   A slots: even tile h0->0 h1->1, odd tile h0->2 h1->3
//   B slots: even tile h0->4 h1->5, odd tile h0->6 h1->7
// Per K-tile phases (quadrant = half): P(0,0) reads A-h0(8)+B-h0(4);
// P(0,1) reads B-h1(4); P(1,0) reads A-h1(8); P(1,1) reads nothing.
// Fragments held in registers across phases -> 24 ds_read_b128/K-tile/wave
// (half of round 2's 48).
// Stage order (slot staged right after its single read phase frees it):
//   P1->s3(A t1 h1), P2->s0(A t2 h0), P3->s4(B t2 h0), P4->s1(A t2 h1),
//   P5->s5(B t2 h1), P6->s2(A t3 h0), P7->s6(B t3 h0), P8->s7(B t3 h1)
// vmcnt(4) at P4 completes {s6,s7,s3,s0}; at P8 completes {s4,s1,s5,s2}:
// every read is covered by a preceding wait (no latency races).

#define STAGE_A(slot, t, h) do { \
    _Pragma("unroll") for (int q_ = 0; q_ < 2; ++q_) { \
        const int r_ = s_row[q_]; \
        const uint16_t* src_ = A + (int64_t)(m0 + ((r_ >> 6) << 7) + ((h) << 6) + (r_ & 63)) * KDIM + ((t) << 6) + s_kc[q_]; \
        __builtin_amdgcn_global_load_lds((__attribute__((address_space(1))) void*)(src_), \
            (__attribute__((address_space(3))) void*)(&lds[slot][(q_ * 512 + tid) * 8]), 16, 0, 0); \
    } } while (0)

#define STAGE_B(slot, t, h) do { \
    _Pragma("unroll") for (int q_ = 0; q_ < 2; ++q_) { \
        const int r_ = s_row[q_]; \
        const uint16_t* src_ = Wb + (int64_t)(n0 + ((r_ >> 5) << 6) + ((h) << 5) + (r_ & 31)) * KDIM + ((t) << 6) + s_kc[q_]; \
        __builtin_amdgcn_global_load_lds((__attribute__((address_space(1))) void*)(src_), \
            (__attribute__((address_space(3))) void*)(&lds[slot][(q_ * 512 + tid) * 8]), 16, 0, 0); \
    } } while (0)

// read logical (slot, srow, kchunk) with swizzle
#define RD(slot, srow, kc) \
    (*(const bf16x8*)((const char*)(&lds[0][0]) + ((slot) * 16384) + ((srow) * 128) + ((((kc) ^ ((srow) & 7))) * 16)))

#define RD_A(tp, h) do { \
    _Pragma("unroll") for (int kk = 0; kk < 2; ++kk) \
        _Pragma("unroll") for (int mf = 0; mf < 4; ++mf) \
            aF[kk][mf] = RD((((tp) & 1) << 1) + (h), wm * 64 + mf * 16 + fr, kk * 4 + kg); \
} while (0)

#define RD_B(dst, tp, h) do { \
    _Pragma("unroll") for (int kk = 0; kk < 2; ++kk) \
        _Pragma("unroll") for (int nf = 0; nf < 2; ++nf) \
            dst[kk][nf] = RD(4 + (((tp) & 1) << 1) + (h), wn * 32 + nf * 16 + fr, kk * 4 + kg); \
} while (0)

#define MM(qm, qn, bsrc) do { \
    _Pragma("unroll") for (int kk = 0; kk < 2; ++kk) \
        _Pragma("unroll") for (int mf = 0; mf < 4; ++mf) \
            _Pragma("unroll") for (int nf = 0; nf < 2; ++nf) \
                acc[(qm) * 4 + mf][(qn) * 2 + nf] = __builtin_amdgcn_mfma_f32_16x16x32_bf16( \
                    aF[kk][mf], bsrc[kk][nf], acc[(qm) * 4 + mf][(qn) * 2 + nf], 0, 0, 0); \
} while (0)

#define PHX(READS, STAGE, MFMAS, WAITC) do { \
    asm volatile("" ::: "memory"); \
    READS; \
    STAGE; \
    asm volatile("" ::: "memory"); \
    __builtin_amdgcn_s_barrier(); \
    asm volatile("s_waitcnt lgkmcnt(0)" ::: "memory"); \
    __builtin_amdgcn_s_setprio(1); \
    MFMAS; \
    __builtin_amdgcn_s_setprio(0); \
    WAITC; \
    __builtin_amdgcn_s_barrier(); \
} while (0)

#define WC4 asm volatile("s_waitcnt vmcnt(4)" ::: "memory")
#define WC0 asm volatile("s_waitcnt vmcnt(0)" ::: "memory")

__global__ __launch_bounds__(512, 2) void lstm_gemm8p_kernel(
    const uint16_t* __restrict__ A,
    const uint16_t* __restrict__ Wb,
    uint16_t* __restrict__ G) {
    __shared__ uint16_t lds[8][8192];  // 128 KiB

    const int tid = threadIdx.x;
    const int lane = tid & 63;
    const int kg = lane >> 4;
    const int fr = lane & 15;
    const int wid = tid >> 6;
    const int wm = wid >> 2;   // 0..1
    const int wn = wid & 3;    // 0..3

    // XCD-aware swizzle: 768 blocks, 768 % 8 == 0 -> simple bijection
    const int bid = blockIdx.x;
    const int swz = (bid & 7) * 96 + (bid >> 3);
    const int mb = swz / 24;
    const int nb = swz - mb * 24;
    const int m0 = mb << 8;
    const int n0 = nb << 8;

    // staging constants: chunk = q*512 + tid -> row, swizzled k-chunk
    int s_row[2], s_kc[2];
#pragma unroll
    for (int q_ = 0; q_ < 2; ++q_) {
        const int chunk = q_ * 512 + tid;
        const int r_ = chunk >> 3;
        const int c_ = chunk & 7;
        s_row[q_] = r_;
        s_kc[q_] = (c_ ^ (r_ & 7)) * 8;  // element offset
    }

    f32x4 acc[8][4] = {};
    bf16x8 aF[2][4];
    bf16x8 bF0[2][2];
    bf16x8 bF1[2][2];

    // prologue: t0 full (s0,s4,s1,s5), t1 h0 (s2,s6), t1 h1 B (s7).
    // s3 (t1 h1 A) is staged in-loop at P1 -> loop is uniform from i=0.
    STAGE_A(0, 0, 0); STAGE_B(4, 0, 0);
    STAGE_A(1, 0, 1); STAGE_B(5, 0, 1);
    STAGE_A(2, 1, 0); STAGE_B(6, 1, 0);
    STAGE_B(7, 1, 1);
    WC4;  // completes s0,s4,s1,s5,s2 ; leaves s6,s7 in flight
    __builtin_amdgcn_s_barrier();

    // 64 K-tiles, 2 per iteration; i=31 is the peeled tail
    for (int i = 0; i < 31; ++i) {
        const int t0 = 2 * i;
        const int t1 = t0 + 1, t2 = t0 + 2, t3 = t0 + 3;
        PHX(RD_A(t0, 0); RD_B(bF0, t0, 0), STAGE_A(3, t1, 1), MM(0, 0, bF0), );
        PHX(RD_B(bF1, t0, 1),              STAGE_A(0, t2, 0), MM(0, 1, bF1), );
        PHX(RD_A(t0, 1),                   STAGE_B(4, t2, 0), MM(1, 0, bF0), );
        PHX(;,                             STAGE_A(1, t2, 1), MM(1, 1, bF1), WC4);
        PHX(RD_A(t1, 0); RD_B(bF0, t1, 0), STAGE_B(5, t2, 1), MM(0, 0, bF0), );
        PHX(RD_B(bF1, t1, 1),              STAGE_A(2, t3, 0), MM(0, 1, bF1), );
        PHX(RD_A(t1, 1),                   STAGE_B(6, t3, 0), MM(1, 0, bF0), );
        PHX(;,                             STAGE_B(7, t3, 1), MM(1, 1, bF1), WC4);
    }
    // tail: t0=62, t1=63; only the s3 stage remains in-range
    PHX(RD_A(62, 0); RD_B(bF0, 62, 0), STAGE_A(3, 63, 1), MM(0, 0, bF0), );
    PHX(RD_B(bF1, 62, 1),              ;,                 MM(0, 1, bF1), );
    PHX(RD_A(62, 1),                   ;,                 MM(1, 0, bF0), );
    PHX(;,                             ;,                 MM(1, 1, bF1), WC0);
    PHX(RD_A(63, 0); RD_B(bF0, 63, 0), ;,                 MM(0, 0, bF0), );
    PHX(RD_B(bF1, 63, 1),              ;,                 MM(0, 1, bF1), );
    PHX(RD_A(63, 1),                   ;,                 MM(1, 0, bF0), );
    PHX(;,                             ;,                 MM(1, 1, bF1), );

    // C-write: D layout col = lane&15, row = (lane>>4)*4 + j
#pragma unroll
    for (int mf = 0; mf < 8; ++mf) {
#pragma unroll
        for (int nf = 0; nf < 4; ++nf) {
            const int n = n0 + wn * 64 + nf * 16 + fr;
            const int64_t mbase = (int64_t)(m0 + wm * 128 + mf * 16 + kg * 4);
#pragma unroll
            for (int j = 0; j < 4; ++j) {
                G[(mbase + j) * NDIM + n] = f2bf(acc[mf][nf][j]);
            }
        }
    }
}

// ---------------- LSTM elementwise epilogue ----------------

__global__ void lstm_epi_kernel(const uint16_t* __restrict__ G,
                                const float* __restrict__ c_prev,
                                const float* __restrict__ b_f,
                                const float* __restrict__ b_o,
                                const float* __restrict__ b_c,
                                float* __restrict__ h_out,
                                float* __restrict__ c_out) {
    const int64_t total = (int64_t)BDIM * HDIM / 8;
    for (int64_t i = (int64_t)blockIdx.x * blockDim.x + threadIdx.x; i < total;
         i += (int64_t)gridDim.x * blockDim.x) {
        const int64_t e = i << 3;
        const int m = (int)(e >> 11);
        const int n = (int)(e & 2047);
        const int64_t gb = (int64_t)m * NDIM + n;
        const short8 fv = *(const short8*)(G + gb);
        const short8 ov = *(const short8*)(G + gb + HDIM);
        const short8 cv = *(const short8*)(G + gb + 2 * HDIM);
        const float4 cp0 = *(const float4*)(c_prev + (int64_t)m * HDIM + n);
        const float4 cp1 = *(const float4*)(c_prev + (int64_t)m * HDIM + n + 4);
        float cp[8] = {cp0.x, cp0.y, cp0.z, cp0.w, cp1.x, cp1.y, cp1.z, cp1.w};
        float hr[8], cr[8];
#pragma unroll
        for (int j = 0; j < 8; ++j) {
            const float fpre = bf2f((uint16_t)fv[j]) + b_f[n + j];
            const float opre = bf2f((uint16_t)ov[j]) + b_o[n + j];
            const float cpre = bf2f((uint16_t)cv[j]) + b_c[n + j];
            const float ft = fast_sigmoid(fpre);
            const float ot = fast_sigmoid(opre);
            const float ch = fast_tanh(cpre);
            const float ct = ft * cp[j] + (1.0f - ft) * ch;
            hr[j] = ot * fast_tanh(ct);
            cr[j] = ct;
        }
        float4 h0 = {hr[0], hr[1], hr[2], hr[3]};
        float4 h1 = {hr[4], hr[5], hr[6], hr[7]};
        float4 c0 = {cr[0], cr[1], cr[2], cr[3]};
        float4 c1 = {cr[4], cr[5], cr[6], cr[7]};
        *(float4*)(h_out + (int64_t)m * HDIM + n) = h0;
        *(float4*)(h_out + (int64_t)m * HDIM + n + 4) = h1;
        *(float4*)(c_out + (int64_t)m * HDIM + n) = c0;
        *(float4*)(c_out + (int64_t)m * HDIM + n + 4) = c1;
    }
}

extern "C" void kernel_launch(void* const* d_in, const int* in_sizes, int n_in,
                              void* d_out, int out_size, void* d_ws, size_t ws_size,
                              hipStream_t stream) {
    const float* x_t   = (const float*)d_in[0];
    const float* h_t_1 = (const float*)d_in[1];
    const float* c_t_1 = (const float*)d_in[2];
    const float* W_f   = (const float*)d_in[3];
    const float* b_f   = (const float*)d_in[4];
    const float* W_o   = (const float*)d_in[5];
    const float* b_o   = (const float*)d_in[6];
    const float* W_c   = (const float*)d_in[7];
    const float* b_c   = (const float*)d_in[8];

    uint16_t* xh  = (uint16_t*)d_ws;                            // 64 MiB
    uint16_t* Wbf = xh + (size_t)BDIM * KDIM;                   // 48 MiB
    uint16_t* G   = Wbf + (size_t)NDIM * KDIM;                  // 96 MiB

    float* h_out = (float*)d_out;
    float* c_out = h_out + (size_t)BDIM * HDIM;

    cvt_xh_kernel<<<2048, 256, 0, stream>>>(x_t, h_t_1, xh);
    cvt_w_kernel<<<2048, 256, 0, stream>>>(W_f, W_o, W_c, Wbf);
    lstm_gemm8p_kernel<<<768, 512, 0, stream>>>(xh, Wbf, G);
    lstm_epi_kernel<<<2048, 256, 0, stream>>>(G, c_t_1, b_f, b_o, b_c,
                                              h_out, c_out);
}